// Round 13
// baseline (10060.422 us; speedup 1.0000x reference)
//
#include <hip/hip_runtime.h>
#include <cstdint>
#include <cstddef>

#define BB 512   // batch
#define TT 512   // seq len
#define HH 100   // hidden
#define G4 400   // 4*H

typedef __attribute__((ext_vector_type(8))) short bf16x8;
typedef __attribute__((ext_vector_type(4))) float f32x4;

static __device__ inline short tobf(float v) {   // round-to-nearest-even bf16
    const unsigned u = __float_as_uint(v);
    return (short)((u + 0x7fffu + ((u >> 16) & 1u)) >> 16);
}

// ---------------------------------------------------------------------------
// MFMA recurrent kernel: full 512 steps of one layer, 32 blocks x 512 thr.
// Block owns 16 batch elems (= MFMA M). Whh row-permuted col' = 4u+g and
// bf16-staged in LDS [400][136]; W-fragments gathered ONCE into registers
// (AGPR parking is fine: MFMA reads AGPRs natively — sidesteps the r3-r11
// allocator war), LDS then clobbered and reused as the h double-buffer.
// Per step per wave: 4 ds_read_b128 (A=h frags) + 14 mfma_16x16x32_bf16 +
// in-reg activations (gate = lane&3) + shfl_xor(2)/(1) gate combine +
// f-lane (lane&3==1) c/h update + bf16 h writeback. ONE barrier/step.
// acc initialized from gin (xc, fp32-exact) -> only Whh is bf16 (~2^-9).
// C/D layout (HW-verified r12): col=lane&15, row=(lane>>4)*4+reg.
// ---------------------------------------------------------------------------
template<bool IS_L0, bool WRITE_DROP>
__global__ __launch_bounds__(512, 1)
void rec_mfma(const float* __restrict__ x,       // [B][T] (layer0, IN=1)
              const float* __restrict__ xc,      // [T*B][400] (layers>0)
              const float* __restrict__ Whh_l,   // [400][100]
              const float* __restrict__ Wih0,    // [400] (layer0)
              const float* __restrict__ bih_l,   // [400] (layer0)
              const float* __restrict__ bhh_l,   // [400] (layer0)
              const float* __restrict__ dmask_l, // [B][T][100] (if WRITE_DROP)
              float* __restrict__ hdrop,         // [T][B][100] (if WRITE_DROP)
              float* __restrict__ st_h)          // [B][100] (last h, layer 3)
{
    __shared__ short lds[400 * 136];   // 108.8 KB: W stage, then h dbuf

    const int tid = threadIdx.x;
    const int wv  = tid >> 6;          // wave 0..7
    const int ln  = tid & 63;
    const int lr  = ln & 15;           // col-in-tile / elem-row index
    const int lk  = ln >> 4;           // k/row group 0..3
    const int g   = ln & 3;            // gate of this lane's col'
    const bool isf = (g == 1);
    const bool isg = (g == 2);
    const int b0  = blockIdx.x * 16;

    // --- stage Whh permuted+bf16 into lds[col'*136 + k] (k>=100 -> 0) ---
    for (int i = tid; i < 400 * 136; i += 512) {
        const int c = i / 136, k = i - c * 136;
        short v = 0;
        if (k < HH) {
            const int u = c >> 2, gg = c & 3;
            v = tobf(Whh_l[(size_t)(gg * HH + u) * HH + k]);
        }
        lds[i] = v;
    }
    __syncthreads();

    // --- gather W-fragments (held in VGPR/AGPR for the whole kernel) ---
    bf16x8 wf[4][4];                   // [tile slot][kc]
    #pragma unroll
    for (int ti = 0; ti < 4; ++ti) {
        const int tl = wv + ti * 8;
        if (tl < 25) {
            const int col = tl * 16 + lr;
            #pragma unroll
            for (int kc = 0; kc < 4; ++kc)
                wf[ti][kc] = *(const bf16x8*)&lds[col * 136 + kc * 32 + lk * 8];
        }
    }
    __syncthreads();

    // --- clobber staged W (kills remat; AGPR fallback is free for MFMA);
    //     zero region doubles as h double-buffer init (incl. k-pad) ---
    for (int i = tid; i < 400 * 136; i += 512) lds[i] = 0;

    // per-tile constants
    int rph[4], uu[4];                 // original gate-row, unit
    float wxv[4], bsv[4];
    #pragma unroll
    for (int ti = 0; ti < 4; ++ti) {
        const int tl = wv + ti * 8;
        if (tl < 25) {
            const int col = tl * 16 + lr;
            rph[ti] = (col & 3) * HH + (col >> 2);
            uu[ti]  = col >> 2;
            if (IS_L0) {
                wxv[ti] = Wih0[rph[ti]];
                bsv[ti] = bih_l[rph[ti]] + bhh_l[rph[ti]];
            }
        }
    }

    float c2[4][4];
    #pragma unroll
    for (int ti = 0; ti < 4; ++ti)
        #pragma unroll
        for (int r = 0; r < 4; ++r) c2[ti][r] = 0.f;

    __syncthreads();

    // --- prefetch t = 0 gate inputs ---
    float ginc[4][4], xcur[4];
    if (IS_L0) {
        #pragma unroll
        for (int r = 0; r < 4; ++r) xcur[r] = x[(size_t)(b0 + lk * 4 + r) * TT];
    } else {
        #pragma unroll
        for (int ti = 0; ti < 4; ++ti) {
            const int tl = wv + ti * 8;
            if (tl < 25) {
                #pragma unroll
                for (int r = 0; r < 4; ++r)
                    ginc[ti][r] = xc[(size_t)(b0 + lk * 4 + r) * G4 + rph[ti]];
            }
        }
    }

    int cur = 0;
    for (int t = 0; t < TT; ++t) {
        const int tn = (t + 1 < TT) ? (t + 1) : t;

        // --- prefetch t+1 ---
        float ginn[4][4], xnxt[4];
        if (IS_L0) {
            #pragma unroll
            for (int r = 0; r < 4; ++r)
                xnxt[r] = x[(size_t)(b0 + lk * 4 + r) * TT + tn];
        } else {
            const size_t base = (size_t)tn * BB * G4;
            #pragma unroll
            for (int ti = 0; ti < 4; ++ti) {
                const int tl = wv + ti * 8;
                if (tl < 25) {
                    #pragma unroll
                    for (int r = 0; r < 4; ++r)
                        ginn[ti][r] = xc[base + (size_t)(b0 + lk * 4 + r) * G4 + rph[ti]];
                }
            }
        }
        // dropout masks for this step (used late; in-step latency hidden)
        float mk[4][4];
        if (WRITE_DROP && isf) {
            #pragma unroll
            for (int ti = 0; ti < 4; ++ti) {
                const int tl = wv + ti * 8;
                if (tl < 25) {
                    #pragma unroll
                    for (int r = 0; r < 4; ++r)
                        mk[ti][r] = dmask_l[(size_t)(b0 + lk * 4 + r) * TT * HH
                                            + (size_t)t * HH + uu[ti]];
                }
            }
        }

        // --- A fragments: h[elem][k] from LDS ---
        bf16x8 af[4];
        #pragma unroll
        for (int kc = 0; kc < 4; ++kc)
            af[kc] = *(const bf16x8*)&lds[cur * 2176 + lr * 136 + kc * 32 + lk * 8];

        // --- MFMA: acc[elem][col'] = gin + h @ Whh' ---
        const int nxt = cur ^ 1;
        #pragma unroll
        for (int ti = 0; ti < 4; ++ti) {
            const int tl = wv + ti * 8;
            if (tl < 25) {
                f32x4 acc;
                if (IS_L0) {
                    #pragma unroll
                    for (int r = 0; r < 4; ++r)
                        acc[r] = fmaf(xcur[r], wxv[ti], bsv[ti]);
                } else {
                    #pragma unroll
                    for (int r = 0; r < 4; ++r) acc[r] = ginc[ti][r];
                }
                #pragma unroll
                for (int kc = 0; kc < 4; ++kc)
                    acc = __builtin_amdgcn_mfma_f32_16x16x32_bf16(
                        af[kc], wf[ti][kc], acc, 0, 0, 0);

                // --- activations + gate combine + state update ---
                #pragma unroll
                for (int r = 0; r < 4; ++r) {
                    const float pre = acc[r];
                    const float E  = __expf(isg ? (pre + pre) : (-pre));
                    const float rr = 1.f / (1.f + E);
                    const float a  = isg ? fmaf(-2.f, rr, 1.f) : rr;  // act
                    const float t2 = __shfl_xor(a, 2);   // f-lane: sig(o)
                    const float pr = a * t2;             // i-lane: i*g
                    const float t1 = __shfl_xor(pr, 1);  // f-lane: i*g
                    if (isf) {
                        const float c = fmaf(a, c2[ti][r], t1);
                        c2[ti][r] = c;
                        const float Ec = __expf(c + c);
                        const float th = 1.f - 2.f / (Ec + 1.f);
                        const float h  = t2 * th;        // sig(o)*tanh(c)
                        const int  e   = lk * 4 + r;
                        lds[nxt * 2176 + e * 136 + uu[ti]] = tobf(h);
                        if (WRITE_DROP)
                            hdrop[((size_t)t * BB + b0 + e) * HH + uu[ti]] =
                                h * mk[ti][r] * 2.f;
                        if (t == TT - 1 && st_h)
                            st_h[(size_t)(b0 + e) * HH + uu[ti]] = h;
                    }
                }
            }
        }
        __syncthreads();
        cur = nxt;
        #pragma unroll
        for (int ti = 0; ti < 4; ++ti)
            #pragma unroll
            for (int r = 0; r < 4; ++r) ginc[ti][r] = ginn[ti][r];
        #pragma unroll
        for (int r = 0; r < 4; ++r) xcur[r] = xnxt[r];
    }
}

// ---------------------------------------------------------------------------
// Input-contribution GEMM for layers 1..3 (known-good fp32, ~280us/launch):
// xc[m][n] = sum_k A[m][k]*W[n][k] + (bih[n]+bhh[n]), M=T*B, N=400, K=100
// tile 128(M)x64(N), 256 threads, 8x4 microtile, LDS 80 KB -> 2 blocks/CU.
// ---------------------------------------------------------------------------
__global__ __launch_bounds__(256, 2)
void xc_gemm(const float* __restrict__ A,     // [M][100]
             const float* __restrict__ W,     // [400][100]
             const float* __restrict__ bih_l, // [400]
             const float* __restrict__ bhh_l, // [400]
             float* __restrict__ xc)          // [M][400]
{
    __shared__ float At[HH][132];
    __shared__ float Bt[HH][68];

    const int tid = threadIdx.x;
    const int n0  = blockIdx.x * 64;
    const size_t m0 = (size_t)blockIdx.y * 128;

    for (int s = tid; s < 128 * 25; s += 256) {
        const int r = s / 25, kq = s - r * 25;
        const float4 v = *(const float4*)&A[(m0 + r) * HH + kq * 4];
        At[kq * 4 + 0][r] = v.x; At[kq * 4 + 1][r] = v.y;
        At[kq * 4 + 2][r] = v.z; At[kq * 4 + 3][r] = v.w;
    }
    for (int s = tid; s < 64 * 25; s += 256) {
        const int r = s / 25, kq = s - r * 25;
        const int col = n0 + r;
        float4 v = {0.f, 0.f, 0.f, 0.f};
        if (col < G4) v = *(const float4*)&W[(size_t)col * HH + kq * 4];
        Bt[kq * 4 + 0][r] = v.x; Bt[kq * 4 + 1][r] = v.y;
        Bt[kq * 4 + 2][r] = v.z; Bt[kq * 4 + 3][r] = v.w;
    }
    __syncthreads();

    const int tx = tid & 15;
    const int ty = tid >> 4;
    float acc[8][4];
    #pragma unroll
    for (int i = 0; i < 8; ++i)
        #pragma unroll
        for (int jj = 0; jj < 4; ++jj) acc[i][jj] = 0.f;

    #pragma unroll 4
    for (int k = 0; k < HH; ++k) {
        const float4 a0 = *(const float4*)&At[k][ty * 8];
        const float4 a1 = *(const float4*)&At[k][ty * 8 + 4];
        const float4 bv = *(const float4*)&Bt[k][tx * 4];
        const float av[8] = {a0.x, a0.y, a0.z, a0.w, a1.x, a1.y, a1.z, a1.w};
        #pragma unroll
        for (int i = 0; i < 8; ++i) {
            acc[i][0] = fmaf(av[i], bv.x, acc[i][0]);
            acc[i][1] = fmaf(av[i], bv.y, acc[i][1]);
            acc[i][2] = fmaf(av[i], bv.z, acc[i][2]);
            acc[i][3] = fmaf(av[i], bv.w, acc[i][3]);
        }
    }

    const int col = n0 + tx * 4;
    if (col < G4) {
        const float4 u = *(const float4*)&bih_l[col];
        const float4 v = *(const float4*)&bhh_l[col];
        const float4 bias = {u.x + v.x, u.y + v.y, u.z + v.z, u.w + v.w};
        #pragma unroll
        for (int i = 0; i < 8; ++i) {
            const size_t r = m0 + ty * 8 + i;
            float4 o = {acc[i][0] + bias.x, acc[i][1] + bias.y,
                        acc[i][2] + bias.z, acc[i][3] + bias.w};
            *(float4*)&xc[r * G4 + col] = o;
        }
    }
}

// ---------------------------------------------------------------------------
__global__ __launch_bounds__(256)
void out_kernel(const float* __restrict__ st_h3,  // [B][100]
                const float* __restrict__ Wout,   // [100]
                const float* __restrict__ bout,   // [1]
                float* __restrict__ out)          // [B]
{
    const int b = blockIdx.x * 256 + threadIdx.x;
    if (b < BB) {
        float sum = bout[0];
        #pragma unroll 4
        for (int k = 0; k < HH; ++k)
            sum = fmaf(st_h3[(size_t)b * HH + k], Wout[k], sum);
        out[b] = sum;
    }
}

// ---------------------------------------------------------------------------
extern "C" void kernel_launch(void* const* d_in, const int* in_sizes, int n_in,
                              void* d_out, int out_size, void* d_ws, size_t ws_size,
                              hipStream_t stream)
{
    const float* x     = (const float*)d_in[0];  // [512][512][1]
    const float* Wih0  = (const float*)d_in[1];  // [400][1]
    const float* WihR  = (const float*)d_in[2];  // [3][400][100]
    const float* Whh   = (const float*)d_in[3];  // [4][400][100]
    const float* bih   = (const float*)d_in[4];  // [4][400]
    const float* bhh   = (const float*)d_in[5];  // [4][400]
    const float* Wout  = (const float*)d_in[6];  // [1][100]
    const float* bout  = (const float*)d_in[7];  // [1]
    const float* dmask = (const float*)d_in[8];  // [3][512][512][100]
    float* out = (float*)d_out;

    float* ws    = (float*)d_ws;
    float* xcb   = ws;                                  // T*B*400
    float* hdrop = xcb + (size_t)TT * BB * G4;          // T*B*100
    float* sth   = hdrop + (size_t)TT * BB * HH;        // B*100

    const dim3 rgrid(BB / 16), rblk(512);
    const dim3 ggrid(7, (TT * BB) / 128), gblk(256);

    // layer 0 (input dim 1 fused)
    rec_mfma<true, true><<<rgrid, rblk, 0, stream>>>(
        x, nullptr, Whh, Wih0, bih, bhh, dmask,
        hdrop, nullptr);
    // layers 1..3
    for (int l = 1; l < 4; ++l) {
        xc_gemm<<<ggrid, gblk, 0, stream>>>(
            hdrop, WihR + (size_t)(l - 1) * G4 * HH,
            bih + l * G4, bhh + l * G4, xcb);
        if (l < 3) {
            rec_mfma<false, true><<<rgrid, rblk, 0, stream>>>(
                nullptr, xcb, Whh + (size_t)l * G4 * HH,
                nullptr, nullptr, nullptr,
                dmask + (size_t)l * BB * TT * HH,
                hdrop, nullptr);
        } else {
            rec_mfma<false, false><<<rgrid, rblk, 0, stream>>>(
                nullptr, xcb, Whh + (size_t)l * G4 * HH,
                nullptr, nullptr, nullptr,
                nullptr,
                nullptr, sth);
        }
    }
    out_kernel<<<dim3(2), dim3(256), 0, stream>>>(sth, Wout, bout, out);
}

// Round 14
// 7499.132 us; speedup vs baseline: 1.3415x; 1.3415x over previous
//
#include <hip/hip_runtime.h>
#include <cstdint>
#include <cstddef>

#define BB 512   // batch
#define TT 512   // seq len
#define HH 100   // hidden
#define G4 400   // 4*H
#define WSTRIDE 51200          // 400*128 shorts per layer weight slab
#define TSTRIDE 1600           // 16*100 shorts per step per block
#define DSTRIDE ((size_t)BB * TT * HH)   // dmask/dpk per-layer elems

typedef __attribute__((ext_vector_type(8))) short bf16x8;
typedef __attribute__((ext_vector_type(4))) float f32x4;

static __device__ inline short tobf(float v) {   // round-to-nearest-even bf16
    const unsigned u = __float_as_uint(v);
    return (short)((u + 0x7fffu + ((u >> 16) & 1u)) >> 16);
}
static __device__ inline float frombf(short s) {
    return __uint_as_float(((unsigned)(unsigned short)s) << 16);
}
static __device__ inline bf16x8 ld8u(const short* p) {  // 8B-aligned 8-short load
    const short4 a = *(const short4*)p;
    const short4 b = *(const short4*)(p + 4);
    bf16x8 v;
    v[0] = a.x; v[1] = a.y; v[2] = a.z; v[3] = a.w;
    v[4] = b.x; v[5] = b.y; v[6] = b.z; v[7] = b.w;
    return v;
}

// ---------------------------------------------------------------------------
// Weight prep: permute rows to col' = 4u+g, bf16, zero-pad K 100->128.
// wihb[3][400][128] from WihR, whhb[4][400][128] from Whh.
// ---------------------------------------------------------------------------
__global__ __launch_bounds__(256)
void wprep(const float* __restrict__ WihR, const float* __restrict__ Whh,
           short* __restrict__ wihb, short* __restrict__ whhb)
{
    const int N1 = 3 * WSTRIDE, N2 = 4 * WSTRIDE;
    for (int i = blockIdx.x * 256 + threadIdx.x; i < N1 + N2;
         i += gridDim.x * 256) {
        if (i < N1) {
            const int l = i / WSTRIDE, c = (i / 128) % 400, k = i & 127;
            const int u = c >> 2, g = c & 3;
            float v = 0.f;
            if (k < HH) v = WihR[(size_t)l * G4 * HH + (size_t)(g * HH + u) * HH + k];
            wihb[i] = tobf(v);
        } else {
            const int j = i - N1;
            const int l = j / WSTRIDE, c = (j / 128) % 400, k = j & 127;
            const int u = c >> 2, g = c & 3;
            float v = 0.f;
            if (k < HH) v = Whh[(size_t)l * G4 * HH + (size_t)(g * HH + u) * HH + k];
            whhb[j] = tobf(v);
        }
    }
}

// ---------------------------------------------------------------------------
// Mask pack: dmask float {0,1} -> uint8 {0,2} (dropout scale 1/(1-0.5) folded).
// ---------------------------------------------------------------------------
__global__ __launch_bounds__(256)
void dpack(const float* __restrict__ dmask, unsigned char* __restrict__ dpk)
{
    const size_t n4 = (size_t)3 * DSTRIDE / 4;
    for (size_t i = blockIdx.x * 256 + threadIdx.x; i < n4;
         i += (size_t)gridDim.x * 256) {
        const float4 v = ((const float4*)dmask)[i];
        uchar4 o;
        o.x = v.x != 0.f ? 2 : 0;  o.y = v.y != 0.f ? 2 : 0;
        o.z = v.z != 0.f ? 2 : 0;  o.w = v.w != 0.f ? 2 : 0;
        ((uchar4*)dpk)[i] = o;
    }
}

// ---------------------------------------------------------------------------
// Fused recurrent layer: gates = bias + MFMA(Wih', prevH[t]) + MFMA(Whh', h).
// 32 blocks x 512 thr (8 waves); block owns 16 batch elems for ALL layers ->
// layer l's output slab (bf16, block-local [t][16][100]) IS layer l+1's input.
// W' bf16-staged in LDS -> fragments gathered once -> LDS clobbered (resident
// VGPR/AGPR, r13-verified; MFMA reads AGPRs natively). Per step: 4 LDS A-frags
// (h) + 4 prefetched prev-frags + <=8 MFMA/tile + in-reg acts (gate = lr&3) +
// 2 shfl_xor + f-lane c/h + ONE barrier + cooperative masked bf16 writeback.
// C/D layout HW-verified (r12/r13): col=lane&15, row=(lane>>4)*4+reg.
// ---------------------------------------------------------------------------
template<bool IS_L0, bool WRITE_NEXT>
__global__ __launch_bounds__(512, 1)
void rec_fused(const float* __restrict__ x,        // [B][T] (L0 input)
               const short* __restrict__ prevSlab, // [32][512][16][100] bf16
               const short* __restrict__ whhb,     // [400][128] bf16 permuted
               const short* __restrict__ wihb,     // [400][128] (layers>0)
               const float* __restrict__ Wih0,     // [400] (L0)
               const float* __restrict__ bih_l,    // [400]
               const float* __restrict__ bhh_l,    // [400]
               const unsigned char* __restrict__ dpk_l, // [B][T][100] (if WRITE_NEXT)
               short* __restrict__ nextSlab,       // [32][512][16][100] (if WRITE_NEXT)
               float* __restrict__ st_h)           // [B][100] (layer 3)
{
    __shared__ short lds[400 * 128];   // 102.4 KB: W stage, then h dbuf

    const int tid = threadIdx.x;
    const int wv  = tid >> 6;          // wave 0..7
    const int ln  = tid & 63;
    const int lr  = ln & 15;           // A-row (elem) / B-col index
    const int lk  = ln >> 4;           // k-group 0..3
    const int g   = lr & 3;            // gate of this lane's col'
    const bool isf = (g == 1);
    const bool isg = (g == 2);
    const int b0  = blockIdx.x * 16;

    // ---- stage + gather Whh' ----
    {
        const uint2* src = (const uint2*)whhb;
        uint2* dst = (uint2*)lds;
        for (int i = tid; i < 400 * 128 / 4; i += 512) dst[i] = src[i];
    }
    __syncthreads();

    int rph[4], uu[4];
    bf16x8 wfh[4][4];
    #pragma unroll
    for (int ti = 0; ti < 4; ++ti) {
        const int tl  = wv + ti * 8;
        const int tlc = (tl < 25) ? tl : 24;
        const int col = tlc * 16 + lr;
        rph[ti] = (col & 3) * HH + (col >> 2);
        uu[ti]  = col >> 2;
        #pragma unroll
        for (int kc = 0; kc < 4; ++kc)
            wfh[ti][kc] = *(const bf16x8*)&lds[col * 128 + kc * 32 + lk * 8];
    }
    __syncthreads();

    bf16x8 wfi[4][4];
    if (!IS_L0) {
        const uint2* src = (const uint2*)wihb;
        uint2* dst = (uint2*)lds;
        for (int i = tid; i < 400 * 128 / 4; i += 512) dst[i] = src[i];
        __syncthreads();
        #pragma unroll
        for (int ti = 0; ti < 4; ++ti) {
            const int tl  = wv + ti * 8;
            const int tlc = (tl < 25) ? tl : 24;
            const int col = tlc * 16 + lr;
            #pragma unroll
            for (int kc = 0; kc < 4; ++kc)
                wfi[ti][kc] = *(const bf16x8*)&lds[col * 128 + kc * 32 + lk * 8];
        }
        __syncthreads();
    }

    // ---- clobber staging (kills remat) == zero h double-buffer ----
    {
        const uint2 z = {0u, 0u};
        uint2* dst = (uint2*)lds;
        for (int i = tid; i < 400 * 128 / 4; i += 512) dst[i] = z;
    }

    float bs[4], wx[4];
    #pragma unroll
    for (int ti = 0; ti < 4; ++ti) {
        bs[ti] = bih_l[rph[ti]] + bhh_l[rph[ti]];
        if (IS_L0) wx[ti] = Wih0[rph[ti]];
    }

    float c2[4][4];
    #pragma unroll
    for (int ti = 0; ti < 4; ++ti)
        #pragma unroll
        for (int r = 0; r < 4; ++r) c2[ti][r] = 0.f;

    // writer roles
    const bool isWr = WRITE_NEXT && (tid < 400);
    const int  welem = tid / 25, wc4 = tid % 25;
    const unsigned char* mbase = nullptr;
    if (isWr) mbase = dpk_l + ((size_t)(b0 + welem) * TT) * HH + wc4 * 4;
    short* nbase = nullptr;
    if (WRITE_NEXT)
        nbase = nextSlab + (size_t)blockIdx.x * TT * TSTRIDE + welem * HH + wc4 * 4;

    const short* pbase = nullptr;
    if (!IS_L0)
        pbase = prevSlab + (size_t)blockIdx.x * TT * TSTRIDE + (size_t)lr * HH;

    __syncthreads();

    // ---- prefetch t = 0 ----
    bf16x8 pac[4], pan[4];
    float xcur[4], xnxt[4];
    uchar4 mkb = {0, 0, 0, 0}, mkn = {0, 0, 0, 0};
    if (IS_L0) {
        #pragma unroll
        for (int r = 0; r < 4; ++r) xcur[r] = x[(size_t)(b0 + lk * 4 + r) * TT];
    } else {
        const short* rp = pbase;
        pac[0] = ld8u(rp + lk * 8);
        pac[1] = ld8u(rp + 32 + lk * 8);
        pac[2] = ld8u(rp + 64 + lk * 8);
        pac[3] = (bf16x8){0, 0, 0, 0, 0, 0, 0, 0};
        if (lk == 0) {
            const short4 v = *(const short4*)(rp + 96);
            pac[3][0] = v.x; pac[3][1] = v.y; pac[3][2] = v.z; pac[3][3] = v.w;
        }
    }
    if (isWr) mkb = *(const uchar4*)mbase;

    int cur = 0;
    for (int t = 0; t < TT; ++t) {
        const int tn = (t + 1 < TT) ? (t + 1) : t;

        // ---- prefetch t+1 ----
        if (IS_L0) {
            #pragma unroll
            for (int r = 0; r < 4; ++r)
                xnxt[r] = x[(size_t)(b0 + lk * 4 + r) * TT + tn];
        } else {
            const short* rp = pbase + (size_t)tn * TSTRIDE;
            pan[0] = ld8u(rp + lk * 8);
            pan[1] = ld8u(rp + 32 + lk * 8);
            pan[2] = ld8u(rp + 64 + lk * 8);
            pan[3] = (bf16x8){0, 0, 0, 0, 0, 0, 0, 0};
            if (lk == 0) {
                const short4 v = *(const short4*)(rp + 96);
                pan[3][0] = v.x; pan[3][1] = v.y; pan[3][2] = v.z; pan[3][3] = v.w;
            }
        }
        if (isWr) mkn = *(const uchar4*)(mbase + (size_t)tn * HH);

        // ---- A fragments (own h) from LDS ----
        bf16x8 af[4];
        #pragma unroll
        for (int kc = 0; kc < 4; ++kc)
            af[kc] = *(const bf16x8*)&lds[cur * 2176 + lr * 136 + kc * 32 + lk * 8];

        const int nxt = cur ^ 1;
        #pragma unroll
        for (int ti = 0; ti < 4; ++ti) {
            const int tl = wv + ti * 8;
            if (tl < 25) {
                f32x4 acc;
                if (IS_L0) {
                    #pragma unroll
                    for (int r = 0; r < 4; ++r)
                        acc[r] = fmaf(xcur[r], wx[ti], bs[ti]);
                } else {
                    #pragma unroll
                    for (int r = 0; r < 4; ++r) acc[r] = bs[ti];
                    #pragma unroll
                    for (int kc = 0; kc < 4; ++kc)
                        acc = __builtin_amdgcn_mfma_f32_16x16x32_bf16(
                            pac[kc], wfi[ti][kc], acc, 0, 0, 0);
                }
                #pragma unroll
                for (int kc = 0; kc < 4; ++kc)
                    acc = __builtin_amdgcn_mfma_f32_16x16x32_bf16(
                        af[kc], wfh[ti][kc], acc, 0, 0, 0);

                // ---- activations + gate combine + state update ----
                #pragma unroll
                for (int r = 0; r < 4; ++r) {
                    const float pre = acc[r];
                    const float E  = __expf(isg ? (pre + pre) : (-pre));
                    const float rr = 1.f / (1.f + E);
                    const float a  = isg ? fmaf(-2.f, rr, 1.f) : rr;
                    const float t2 = __shfl_xor(a, 2);   // f-lane: sig(o)
                    const float pr = a * t2;             // i-lane: i*g
                    const float t1 = __shfl_xor(pr, 1);  // f-lane: i*g
                    if (isf) {
                        const float c = fmaf(a, c2[ti][r], t1);
                        c2[ti][r] = c;
                        const float Ec = __expf(c + c);
                        const float th = 1.f - 2.f / (Ec + 1.f);
                        const float h  = t2 * th;        // sig(o)*tanh(c)
                        const int  e   = lk * 4 + r;
                        lds[nxt * 2176 + e * 136 + uu[ti]] = tobf(h);
                        if (!WRITE_NEXT && st_h && t == TT - 1)
                            st_h[(size_t)(b0 + e) * HH + uu[ti]] = h;
                    }
                }
            }
        }
        __syncthreads();

        // ---- cooperative masked writeback of this step's h (bf16) ----
        if (isWr) {
            const short4 hv = *(const short4*)&lds[nxt * 2176 + welem * 136 + wc4 * 4];
            short4 ov;
            ov.x = tobf(frombf(hv.x) * (float)mkb.x);
            ov.y = tobf(frombf(hv.y) * (float)mkb.y);
            ov.z = tobf(frombf(hv.z) * (float)mkb.z);
            ov.w = tobf(frombf(hv.w) * (float)mkb.w);
            *(short4*)(nbase + (size_t)t * TSTRIDE) = ov;
        }

        cur = nxt;
        mkb = mkn;
        if (IS_L0) {
            #pragma unroll
            for (int r = 0; r < 4; ++r) xcur[r] = xnxt[r];
        } else {
            #pragma unroll
            for (int kc = 0; kc < 4; ++kc) pac[kc] = pan[kc];
        }
    }
}

// ---------------------------------------------------------------------------
__global__ __launch_bounds__(256)
void out_kernel(const float* __restrict__ st_h3,  // [B][100]
                const float* __restrict__ Wout,   // [100]
                const float* __restrict__ bout,   // [1]
                float* __restrict__ out)          // [B]
{
    const int b = blockIdx.x * 256 + threadIdx.x;
    if (b < BB) {
        float sum = bout[0];
        #pragma unroll 4
        for (int k = 0; k < HH; ++k)
            sum = fmaf(st_h3[(size_t)b * HH + k], Wout[k], sum);
        out[b] = sum;
    }
}

// ---------------------------------------------------------------------------
extern "C" void kernel_launch(void* const* d_in, const int* in_sizes, int n_in,
                              void* d_out, int out_size, void* d_ws, size_t ws_size,
                              hipStream_t stream)
{
    const float* x     = (const float*)d_in[0];  // [512][512][1]
    const float* Wih0  = (const float*)d_in[1];  // [400][1]
    const float* WihR  = (const float*)d_in[2];  // [3][400][100]
    const float* Whh   = (const float*)d_in[3];  // [4][400][100]
    const float* bih   = (const float*)d_in[4];  // [4][400]
    const float* bhh   = (const float*)d_in[5];  // [4][400]
    const float* Wout  = (const float*)d_in[6];  // [1][100]
    const float* bout  = (const float*)d_in[7];  // [1]
    const float* dmask = (const float*)d_in[8];  // [3][512][512][100]
    float* out = (float*)d_out;

    // ws carve (bytes)
    char* base = (char*)d_ws;
    float* sth = (float*)base;                 base += (size_t)BB * HH * 4;
    short* wihb = (short*)base;                base += (size_t)3 * WSTRIDE * 2;
    short* whhb = (short*)base;                base += (size_t)4 * WSTRIDE * 2;
    short* hsl0 = (short*)base;                base += (size_t)32 * TT * TSTRIDE * 2;
    short* hsl1 = (short*)base;                base += (size_t)32 * TT * TSTRIDE * 2;
    short* hsl2 = (short*)base;                base += (size_t)32 * TT * TSTRIDE * 2;
    unsigned char* dpk = (unsigned char*)base; // 3*DSTRIDE bytes (~78.6 MB)

    wprep<<<dim3(1400), dim3(256), 0, stream>>>(WihR, Whh, wihb, whhb);
    dpack<<<dim3(2048), dim3(256), 0, stream>>>(dmask, dpk);

    const dim3 rgrid(BB / 16), rblk(512);

    // layer 0
    rec_fused<true, true><<<rgrid, rblk, 0, stream>>>(
        x, nullptr, whhb, nullptr, Wih0, bih, bhh,
        dpk, hsl0, nullptr);
    // layer 1
    rec_fused<false, true><<<rgrid, rblk, 0, stream>>>(
        nullptr, hsl0, whhb + WSTRIDE, wihb, nullptr,
        bih + G4, bhh + G4, dpk + DSTRIDE, hsl1, nullptr);
    // layer 2
    rec_fused<false, true><<<rgrid, rblk, 0, stream>>>(
        nullptr, hsl1, whhb + 2 * WSTRIDE, wihb + WSTRIDE, nullptr,
        bih + 2 * G4, bhh + 2 * G4, dpk + 2 * DSTRIDE, hsl2, nullptr);
    // layer 3
    rec_fused<false, false><<<rgrid, rblk, 0, stream>>>(
        nullptr, hsl2, whhb + 3 * WSTRIDE, wihb + 2 * WSTRIDE, nullptr,
        bih + 3 * G4, bhh + 3 * G4, nullptr, nullptr, sth);

    out_kernel<<<dim3(2), dim3(256), 0, stream>>>(sth, Wout, bout, out);
}